// Round 12
// baseline (411.303 us; speedup 1.0000x reference)
//
#include <hip/hip_runtime.h>
#include <hip/hip_bf16.h>

typedef __bf16 bf16_t;
typedef __bf16 bf16x8 __attribute__((ext_vector_type(8)));
typedef __bf16 bf16x4 __attribute__((ext_vector_type(4)));
typedef float  f32x4  __attribute__((ext_vector_type(4)));
typedef unsigned long long u64;

#define N_NODES 100000
#define N_EDGES 1600000
#define IN_C    128
#define OUT_C   64
#define EDGE_D  64
#define NBKT    1563      // ceil(100000 / 64) buckets of 64 dst nodes
#define CH      16384     // edges per scatter/hist block
#define NCHUNK  98        // ceil(1600000 / 16384)

// ---------------- Kernel A: node GEMM (k,q,v,skip) ----------------
__global__ __launch_bounds__(256) void node_gemm_kernel(
    const float* __restrict__ x,
    const float* __restrict__ Wk, const float* __restrict__ bk,
    const float* __restrict__ Wq, const float* __restrict__ bq,
    const float* __restrict__ Wv, const float* __restrict__ bv,
    const float* __restrict__ Ws, const float* __restrict__ bs,
    bf16_t* __restrict__ kqv,   // [3][N][64] bf16
    float*  __restrict__ agg)   // [N][64] f32 (skip-init)
{
    const int w  = threadIdx.x >> 6;
    const int l  = threadIdx.x & 63;
    const int lr = l & 15;
    const int lg = l >> 4;

    const float* W; const float* b;
    if      (w == 0) { W = Wk; b = bk; }
    else if (w == 1) { W = Wq; b = bq; }
    else if (w == 2) { W = Wv; b = bv; }
    else             { W = Ws; b = bs; }

    bf16x8 Bf[4][4];
    #pragma unroll
    for (int ct = 0; ct < 4; ++ct)
        #pragma unroll
        for (int ks = 0; ks < 4; ++ks)
            #pragma unroll
            for (int j = 0; j < 8; ++j)
                Bf[ct][ks][j] = (bf16_t)W[(ks*32 + lg*8 + j)*OUT_C + ct*16 + lr];

    float biasv[4];
    #pragma unroll
    for (int ct = 0; ct < 4; ++ct) biasv[ct] = b[ct*16 + lr];

    const int NTILES = N_NODES / 32;  // 3125
    for (int tile = blockIdx.x; tile < NTILES; tile += gridDim.x) {
        const int n0 = tile * 32;
        f32x4 acc[2][4];
        #pragma unroll
        for (int rt = 0; rt < 2; ++rt)
            #pragma unroll
            for (int ct = 0; ct < 4; ++ct)
                acc[rt][ct] = (f32x4){0.f, 0.f, 0.f, 0.f};

        #pragma unroll
        for (int ks = 0; ks < 4; ++ks) {
            const float* p0 = x + (size_t)(n0 + lr)      * IN_C + ks*32 + lg*8;
            const float* p1 = x + (size_t)(n0 + 16 + lr) * IN_C + ks*32 + lg*8;
            f32x4 v00 = *reinterpret_cast<const f32x4*>(p0);
            f32x4 v01 = *reinterpret_cast<const f32x4*>(p0 + 4);
            f32x4 v10 = *reinterpret_cast<const f32x4*>(p1);
            f32x4 v11 = *reinterpret_cast<const f32x4*>(p1 + 4);
            bf16x8 a0, a1;
            #pragma unroll
            for (int j = 0; j < 4; ++j) {
                a0[j] = (bf16_t)v00[j]; a0[4+j] = (bf16_t)v01[j];
                a1[j] = (bf16_t)v10[j]; a1[4+j] = (bf16_t)v11[j];
            }
            #pragma unroll
            for (int ct = 0; ct < 4; ++ct) {
                acc[0][ct] = __builtin_amdgcn_mfma_f32_16x16x32_bf16(a0, Bf[ct][ks], acc[0][ct], 0, 0, 0);
                acc[1][ct] = __builtin_amdgcn_mfma_f32_16x16x32_bf16(a1, Bf[ct][ks], acc[1][ct], 0, 0, 0);
            }
        }

        #pragma unroll
        for (int rt = 0; rt < 2; ++rt)
            #pragma unroll
            for (int ct = 0; ct < 4; ++ct)
                #pragma unroll
                for (int r = 0; r < 4; ++r) {
                    const int row = n0 + rt*16 + lg*4 + r;
                    const int col = ct*16 + lr;
                    const float val = acc[rt][ct][r] + biasv[ct];
                    if (w < 3) kqv[(size_t)w * N_NODES * OUT_C + (size_t)row * OUT_C + col] = (bf16_t)val;
                    else       agg[(size_t)row * OUT_C + col] = val;
                }
    }
}

// ---------------- pass 1: bucket sort (64-node buckets), 8B payload ----------------
__global__ __launch_bounds__(256) void histB_kernel(const int* __restrict__ dst,
                                                    unsigned* __restrict__ cnt) {
    __shared__ unsigned h[NBKT];
    const int t = threadIdx.x;
    for (int i = t; i < NBKT; i += 256) h[i] = 0u;
    __syncthreads();
    const int cbase = blockIdx.x * CH;
    for (int it = 0; it < 16; ++it) {
        const int i = cbase + (it*256 + t)*4;
        if (i < N_EDGES) {
            int4 d = *reinterpret_cast<const int4*>(dst + i);
            atomicAdd(&h[d.x >> 6], 1u);
            atomicAdd(&h[d.y >> 6], 1u);
            atomicAdd(&h[d.z >> 6], 1u);
            atomicAdd(&h[d.w >> 6], 1u);
        }
    }
    __syncthreads();
    for (int i = t; i < NBKT; i += 256)
        if (h[i]) atomicAdd(&cnt[i], h[i]);
}

__global__ __launch_bounds__(256) void scanB_kernel(const unsigned* __restrict__ cnt,
                                                    unsigned* __restrict__ base_,
                                                    unsigned* __restrict__ cursor) {
    __shared__ unsigned s[256];
    const int t = threadIdx.x;
    unsigned v[7]; unsigned sum = 0;
    #pragma unroll
    for (int j = 0; j < 7; ++j) {
        const int i = t*7 + j;
        v[j] = (i < NBKT) ? cnt[i] : 0u;
        sum += v[j];
    }
    s[t] = sum; __syncthreads();
    for (int d = 1; d < 256; d <<= 1) {
        unsigned y = (t >= d) ? s[t-d] : 0u;
        __syncthreads();
        s[t] += y;
        __syncthreads();
    }
    unsigned run = s[t] - sum;   // exclusive prefix
    #pragma unroll
    for (int j = 0; j < 7; ++j) {
        const int i = t*7 + j;
        if (i < NBKT) { base_[i] = run; cursor[i] = run; run += v[j]; }
    }
    if (t == 0) base_[NBKT] = N_EDGES;
}

// payload: eid(21b) | src(17b)<<21 | dst(17b)<<38
__global__ __launch_bounds__(256) void scatterB_kernel(const int* __restrict__ ei,
                                                       unsigned* __restrict__ cursor,
                                                       u64* __restrict__ srtA) {
    __shared__ unsigned h[NBKT];
    const int t = threadIdx.x;
    for (int i = t; i < NBKT; i += 256) h[i] = 0u;
    __syncthreads();
    const int cbase = blockIdx.x * CH;
    const int* dst = ei + N_EDGES;
    for (int it = 0; it < 16; ++it) {
        const int i = cbase + (it*256 + t)*4;
        if (i < N_EDGES) {
            int4 d = *reinterpret_cast<const int4*>(dst + i);
            atomicAdd(&h[d.x >> 6], 1u);
            atomicAdd(&h[d.y >> 6], 1u);
            atomicAdd(&h[d.z >> 6], 1u);
            atomicAdd(&h[d.w >> 6], 1u);
        }
    }
    __syncthreads();
    for (int i = t; i < NBKT; i += 256) {
        unsigned c = h[i];
        if (c) h[i] = atomicAdd(&cursor[i], c);
    }
    __syncthreads();
    for (int it = 0; it < 16; ++it) {
        const int i = cbase + (it*256 + t)*4;
        if (i < N_EDGES) {
            int4 s = *reinterpret_cast<const int4*>(ei + i);
            int4 d = *reinterpret_cast<const int4*>(dst + i);
            unsigned p0 = atomicAdd(&h[d.x >> 6], 1u);
            srtA[p0] = (u64)(unsigned)(i+0) | ((u64)(unsigned)s.x << 21) | ((u64)(unsigned)d.x << 38);
            unsigned p1 = atomicAdd(&h[d.y >> 6], 1u);
            srtA[p1] = (u64)(unsigned)(i+1) | ((u64)(unsigned)s.y << 21) | ((u64)(unsigned)d.y << 38);
            unsigned p2 = atomicAdd(&h[d.z >> 6], 1u);
            srtA[p2] = (u64)(unsigned)(i+2) | ((u64)(unsigned)s.z << 21) | ((u64)(unsigned)d.z << 38);
            unsigned p3 = atomicAdd(&h[d.w >> 6], 1u);
            srtA[p3] = (u64)(unsigned)(i+3) | ((u64)(unsigned)s.w << 21) | ((u64)(unsigned)d.w << 38);
        }
    }
}

// ---------------- pass 2: within-bucket counting sort by dst&63 ----------------
__global__ __launch_bounds__(256) void sortbkt_kernel(const u64* __restrict__ srtA,
                                                      const unsigned* __restrict__ base_,
                                                      u64* __restrict__ srtB) {
    __shared__ unsigned hist[64];
    __shared__ unsigned cur[64];
    const int t = threadIdx.x;
    const unsigned s = base_[blockIdx.x];
    const unsigned e = base_[blockIdx.x + 1];
    if (t < 64) hist[t] = 0u;
    __syncthreads();
    for (unsigned i = s + t; i < e; i += 256) {
        unsigned dlo = (unsigned)(srtA[i] >> 38) & 63u;
        atomicAdd(&hist[dlo], 1u);
    }
    __syncthreads();
    if (t < 64) {  // wave 0: exclusive scan over 64 bins
        unsigned h = hist[t];
        unsigned v = h;
        #pragma unroll
        for (int off = 1; off < 64; off <<= 1) {
            unsigned y = __shfl_up(v, off);
            if (t >= off) v += y;
        }
        cur[t] = v - h;
    }
    __syncthreads();
    for (unsigned i = s + t; i < e; i += 256) {
        u64 p = srtA[i];
        unsigned dlo = (unsigned)(p >> 38) & 63u;
        unsigned pos = atomicAdd(&cur[dlo], 1u);
        srtB[s + pos] = p;
    }
}

// ---------------- Kernel B: R11 + WeT->regs (5 blocks/CU) + permuted cols ----------------
// B-fragments preloaded in registers with column permutation col = lr*4+ct so
// the epilogue reads k/q/v as contiguous bf16x4 (ds_read_b64): 48 scalar LDS
// reads -> 12 wide ones. LDS 27.6KB -> 5 blocks/CU (+25% concurrency).
__global__ __launch_bounds__(256) void edge_seg_kernel(
    const float* __restrict__ ea,
    const u64*   __restrict__ srt,
    const float* __restrict__ We, const float* __restrict__ be,
    const bf16_t* __restrict__ kqv,
    float* __restrict__ agg,
    float* __restrict__ out_ea)
{
    __shared__ bf16_t ktab[4][16][72];    // per-wave staged k rows (by slot dst)
    __shared__ bf16_t qtab[4][16][72];    // per-wave staged q rows
    __shared__ bf16_t vtab[4][16][72];    // per-wave staged v rows

    const int tid = threadIdx.x;
    const int wv  = tid >> 6;
    const int l   = tid & 63;
    const int lr  = l & 15;
    const int lg  = l >> 4;
    const int row8 = l >> 3;   // 0..7
    const int part = l & 7;    // 0..7

    // B fragments in registers, PERMUTED columns: MFMA ct's output col lr
    // corresponds to actual We column lr*4+ct.
    bf16x8 Bf[4][2];
    #pragma unroll
    for (int ct = 0; ct < 4; ++ct)
        #pragma unroll
        for (int ks = 0; ks < 2; ++ks)
            #pragma unroll
            for (int j = 0; j < 8; ++j)
                Bf[ct][ks][j] = (bf16_t)We[(ks*32 + lg*8 + j)*OUT_C + lr*4 + ct];

    float bev[4];
    #pragma unroll
    for (int ct = 0; ct < 4; ++ct) bev[ct] = be[lr*4 + ct];

    const bf16_t* kT = kqv;
    const bf16_t* qT = kqv + (size_t)N_NODES * OUT_C;
    const bf16_t* vT = kqv + (size_t)2 * N_NODES * OUT_C;

    const int wid0 = blockIdx.x * 4 + wv;
    const int nw   = gridDim.x * 4;
    const int NT   = N_EDGES / 16;

    for (int t = wid0; t < NT; t += nw) {
        const int e0 = t * 16;
        const u64 p = srt[e0 + lr];   // slot lr's packed {eid,src,dst}
        const int eidL = (int)(p & 0x1FFFFF);
        const int srcL = (int)((p >> 21) & 0x1FFFF);
        const int dstL = (int)((p >> 38) & 0x1FFFF);

        // ---- A-fragment (slot = lr) + fused out_ea copy ----
        bf16x8 a[2];
        #pragma unroll
        for (int ks = 0; ks < 2; ++ks) {
            const size_t off = (size_t)eidL * EDGE_D + ks*32 + lg*8;
            f32x4 v0 = *reinterpret_cast<const f32x4*>(ea + off);
            f32x4 v1 = *reinterpret_cast<const f32x4*>(ea + off + 4);
            *reinterpret_cast<f32x4*>(out_ea + off)     = v0;
            *reinterpret_cast<f32x4*>(out_ea + off + 4) = v1;
            #pragma unroll
            for (int j = 0; j < 4; ++j) { a[ks][j] = (bf16_t)v0[j]; a[ks][4+j] = (bf16_t)v1[j]; }
        }

        // ---- wide k/q/v row gathers -> per-wave LDS transpose ----
        const int src0 = __shfl(srcL, row8);
        const int src1 = __shfl(srcL, row8 + 8);
        const int dst0 = __shfl(dstL, row8);
        const int dst1 = __shfl(dstL, row8 + 8);
        uint4 gk0 = *reinterpret_cast<const uint4*>(kT + (size_t)dst0 * OUT_C + part*8);
        uint4 gk1 = *reinterpret_cast<const uint4*>(kT + (size_t)dst1 * OUT_C + part*8);
        uint4 gq0 = *reinterpret_cast<const uint4*>(qT + (size_t)src0 * OUT_C + part*8);
        uint4 gq1 = *reinterpret_cast<const uint4*>(qT + (size_t)src1 * OUT_C + part*8);
        uint4 gv0 = *reinterpret_cast<const uint4*>(vT + (size_t)src0 * OUT_C + part*8);
        uint4 gv1 = *reinterpret_cast<const uint4*>(vT + (size_t)src1 * OUT_C + part*8);
        *reinterpret_cast<uint4*>(&ktab[wv][row8    ][part*8]) = gk0;
        *reinterpret_cast<uint4*>(&ktab[wv][row8 + 8][part*8]) = gk1;
        *reinterpret_cast<uint4*>(&qtab[wv][row8    ][part*8]) = gq0;
        *reinterpret_cast<uint4*>(&qtab[wv][row8 + 8][part*8]) = gq1;
        *reinterpret_cast<uint4*>(&vtab[wv][row8    ][part*8]) = gv0;
        *reinterpret_cast<uint4*>(&vtab[wv][row8 + 8][part*8]) = gv1;

        // ---- MFMA e-projection (register B-fragments, permuted cols) ----
        f32x4 ep[4];
        #pragma unroll
        for (int ct = 0; ct < 4; ++ct) {
            f32x4 z = (f32x4){0.f, 0.f, 0.f, 0.f};
            z = __builtin_amdgcn_mfma_f32_16x16x32_bf16(a[0], Bf[ct][0], z, 0, 0, 0);
            ep[ct] = __builtin_amdgcn_mfma_f32_16x16x32_bf16(a[1], Bf[ct][1], z, 0, 0, 0);
        }

        // dst per epilogue slot s = lg*4 + r (broadcast from slot lanes)
        int dR[4];
        #pragma unroll
        for (int r = 0; r < 4; ++r) dR[r] = __shfl(dstL, lg*4 + r);
        const int d0 = dR[0], d1 = dR[1], d2 = dR[2], d3 = dR[3];

        // ---- gate + message: lane lr covers cols lr*4 .. lr*4+3 ----
        float val[4][4];  // [r][ct]
        #pragma unroll
        for (int r = 0; r < 4; ++r) {
            const int s = lg*4 + r;
            bf16x4 k4 = *reinterpret_cast<const bf16x4*>(&ktab[wv][s][lr*4]);
            bf16x4 q4 = *reinterpret_cast<const bf16x4*>(&qtab[wv][s][lr*4]);
            bf16x4 v4 = *reinterpret_cast<const bf16x4*>(&vtab[wv][s][lr*4]);
            #pragma unroll
            for (int ct = 0; ct < 4; ++ct) {
                const float z  = (float)k4[ct] + bev[ct] + (float)q4[ct] + ep[ct][r];
                const float g  = 1.f / (1.f + __expf(-z));
                val[r][ct] = g * (float)v4[ct];
            }
        }

        // ---- in-lane inclusive segmented scan over r ----
        #pragma unroll
        for (int ct = 0; ct < 4; ++ct) {
            if (d1 == d0) val[1][ct] += val[0][ct];
            if (d2 == d1) val[2][ct] += val[1][ct];
            if (d3 == d2) val[3][ct] += val[2][ct];
        }

        // ---- cross-lane-group segmented scan on (S, B) monoid ----
        const int prev_d3 = __shfl(d3, l - 16);
        const int h  = (lg == 0) || (d0 != prev_d3);
        int Bs = h || (d0 != d3);
        float S[4];
        #pragma unroll
        for (int ct = 0; ct < 4; ++ct) S[ct] = val[3][ct];

        {
            float p0 = __shfl(S[0], l-16), p1 = __shfl(S[1], l-16),
                  p2 = __shfl(S[2], l-16), p3 = __shfl(S[3], l-16);
            int  pB = __shfl(Bs, l-16);
            if (lg >= 1) {
                if (!Bs) { S[0] += p0; S[1] += p1; S[2] += p2; S[3] += p3; }
                Bs |= pB;
            }
        }
        {
            float p0 = __shfl(S[0], l-32), p1 = __shfl(S[1], l-32),
                  p2 = __shfl(S[2], l-32), p3 = __shfl(S[3], l-32);
            int  pB = __shfl(Bs, l-32);
            if (lg >= 2) {
                if (!Bs) { S[0] += p0; S[1] += p1; S[2] += p2; S[3] += p3; }
                Bs |= pB;
            }
        }

        float C[4];
        #pragma unroll
        for (int ct = 0; ct < 4; ++ct) C[ct] = __shfl(S[ct], l - 16);

        if (!h) {
            #pragma unroll
            for (int r = 0; r < 4; ++r)
                if (dR[r] == d0) {
                    #pragma unroll
                    for (int ct = 0; ct < 4; ++ct) val[r][ct] += C[ct];
                }
        }

        const int next_d0 = __shfl(d0, l + 16);
        bool lastR[4];
        lastR[0] = (d1 != d0);
        lastR[1] = (d2 != d1);
        lastR[2] = (d3 != d2);
        lastR[3] = (lg == 3) ? true : (next_d0 != d3);

        #pragma unroll
        for (int r = 0; r < 4; ++r) {
            if (lastR[r]) {
                float* row = agg + (size_t)dR[r] * OUT_C + lr*4;
                #pragma unroll
                for (int ct = 0; ct < 4; ++ct)
                    atomicAdd(row + ct, val[r][ct]);
            }
        }
    }
}

// ---------------- Kernel C: finalize ----------------
__global__ __launch_bounds__(256) void finalize_kernel(
    const float* __restrict__ agg,
    const float* __restrict__ u,
    float* __restrict__ out_node,
    float* __restrict__ out_u)
{
    const int gid   = blockIdx.x * blockDim.x + threadIdx.x;
    const int total = N_NODES * OUT_C / 4;
    for (int i = gid; i < total; i += gridDim.x * blockDim.x) {
        f32x4 v = *reinterpret_cast<const f32x4*>(agg + (size_t)i * 4);
        f32x4 o;
        #pragma unroll
        for (int j = 0; j < 4; ++j) o[j] = v[j] > 0.f ? v[j] : 0.f;
        *reinterpret_cast<f32x4*>(out_node + (size_t)i * 4) = o;
    }
    if (gid < 64) out_u[gid] = u[gid];
}

extern "C" void kernel_launch(void* const* d_in, const int* in_sizes, int n_in,
                              void* d_out, int out_size, void* d_ws, size_t ws_size,
                              hipStream_t stream) {
    const float* x  = (const float*)d_in[0];
    const int*   ei = (const int*)  d_in[1];
    const float* ea = (const float*)d_in[2];
    const float* u  = (const float*)d_in[3];
    const float* Wk = (const float*)d_in[4];
    const float* bk = (const float*)d_in[5];
    const float* Wq = (const float*)d_in[6];
    const float* bq = (const float*)d_in[7];
    const float* Wv = (const float*)d_in[8];
    const float* bv = (const float*)d_in[9];
    const float* We = (const float*)d_in[10];
    const float* be = (const float*)d_in[11];
    const float* Ws = (const float*)d_in[12];
    const float* bs = (const float*)d_in[13];

    float* out      = (float*)d_out;
    float* out_node = out;
    float* out_ea   = out + (size_t)N_NODES * OUT_C;
    float* out_u    = out + (size_t)N_NODES * OUT_C + (size_t)N_EDGES * EDGE_D;

    // ws layout
    char* w = (char*)d_ws;
    bf16_t*   kqv    = (bf16_t*)w;                 // 38,400,000 B
    float*    agg    = (float*)(w + 38400000);     // 25,600,000 B -> 64,000,000
    unsigned* cnt    = (unsigned*)(w + 64000000);  //      6,252 B -> 64,008,000
    unsigned* base_  = (unsigned*)(w + 64008000);  //      6,256 B -> 64,016,000
    unsigned* cursor = (unsigned*)(w + 64016000);  //      6,252 B -> 64,024,000
    u64*      srtA   = (u64*)(w + 64024000);       // 12,800,000 B -> 76,824,000
    u64*      srtB   = (u64*)(w + 76824000);       // 12,800,000 B -> 89,624,000

    const int* dst = ei + N_EDGES;

    node_gemm_kernel<<<1024, 256, 0, stream>>>(x, Wk, bk, Wq, bq, Wv, bv, Ws, bs, kqv, agg);
    hipMemsetAsync(cnt, 0, NBKT * sizeof(unsigned), stream);
    histB_kernel<<<NCHUNK, 256, 0, stream>>>(dst, cnt);
    scanB_kernel<<<1, 256, 0, stream>>>(cnt, base_, cursor);
    scatterB_kernel<<<NCHUNK, 256, 0, stream>>>(ei, cursor, srtA);
    sortbkt_kernel<<<NBKT, 256, 0, stream>>>(srtA, base_, srtB);
    edge_seg_kernel<<<2048, 256, 0, stream>>>(ea, srtB, We, be, kqv, agg, out_ea);
    finalize_kernel<<<2048, 256, 0, stream>>>(agg, u, out_node, out_u);
}

// Round 13
// 362.120 us; speedup vs baseline: 1.1358x; 1.1358x over previous
//
#include <hip/hip_runtime.h>
#include <hip/hip_bf16.h>

typedef __bf16 bf16_t;
typedef __bf16 bf16x8 __attribute__((ext_vector_type(8)));
typedef float  f32x4  __attribute__((ext_vector_type(4)));
typedef unsigned long long u64;

#define N_NODES 100000
#define N_EDGES 1600000
#define IN_C    128
#define OUT_C   64
#define EDGE_D  64
#define NBKT    1563      // ceil(100000 / 64) buckets of 64 dst nodes
#define CH      16384     // edges per scatter/hist block
#define NCHUNK  98        // ceil(1600000 / 16384)

// ---------------- Kernel A: node GEMM (k,q,v,skip) + fused dst histogram ----------------
__global__ __launch_bounds__(256) void node_gemm_kernel(
    const float* __restrict__ x,
    const float* __restrict__ Wk, const float* __restrict__ bk,
    const float* __restrict__ Wq, const float* __restrict__ bq,
    const float* __restrict__ Wv, const float* __restrict__ bv,
    const float* __restrict__ Ws, const float* __restrict__ bs,
    const int* __restrict__ dst,
    unsigned* __restrict__ cnt,
    bf16_t* __restrict__ kqv,   // [3][N][64] bf16
    float*  __restrict__ agg)   // [N][64] f32 (skip-init)
{
    // blocks >= 1024: histogram over a 16384-edge chunk
    if (blockIdx.x >= 1024) {
        __shared__ unsigned h[NBKT];
        const int t = threadIdx.x;
        for (int i = t; i < NBKT; i += 256) h[i] = 0u;
        __syncthreads();
        const int cbase = (blockIdx.x - 1024) * CH;
        for (int it = 0; it < 16; ++it) {
            const int i = cbase + (it*256 + t)*4;
            if (i < N_EDGES) {
                int4 d = *reinterpret_cast<const int4*>(dst + i);
                atomicAdd(&h[d.x >> 6], 1u);
                atomicAdd(&h[d.y >> 6], 1u);
                atomicAdd(&h[d.z >> 6], 1u);
                atomicAdd(&h[d.w >> 6], 1u);
            }
        }
        __syncthreads();
        for (int i = t; i < NBKT; i += 256)
            if (h[i]) atomicAdd(&cnt[i], h[i]);
        return;
    }

    const int w  = threadIdx.x >> 6;
    const int l  = threadIdx.x & 63;
    const int lr = l & 15;
    const int lg = l >> 4;

    const float* W; const float* b;
    if      (w == 0) { W = Wk; b = bk; }
    else if (w == 1) { W = Wq; b = bq; }
    else if (w == 2) { W = Wv; b = bv; }
    else             { W = Ws; b = bs; }

    bf16x8 Bf[4][4];
    #pragma unroll
    for (int ct = 0; ct < 4; ++ct)
        #pragma unroll
        for (int ks = 0; ks < 4; ++ks)
            #pragma unroll
            for (int j = 0; j < 8; ++j)
                Bf[ct][ks][j] = (bf16_t)W[(ks*32 + lg*8 + j)*OUT_C + ct*16 + lr];

    float biasv[4];
    #pragma unroll
    for (int ct = 0; ct < 4; ++ct) biasv[ct] = b[ct*16 + lr];

    const int NTILES = N_NODES / 32;  // 3125
    for (int tile = blockIdx.x; tile < NTILES; tile += 1024) {
        const int n0 = tile * 32;
        f32x4 acc[2][4];
        #pragma unroll
        for (int rt = 0; rt < 2; ++rt)
            #pragma unroll
            for (int ct = 0; ct < 4; ++ct)
                acc[rt][ct] = (f32x4){0.f, 0.f, 0.f, 0.f};

        #pragma unroll
        for (int ks = 0; ks < 4; ++ks) {
            const float* p0 = x + (size_t)(n0 + lr)      * IN_C + ks*32 + lg*8;
            const float* p1 = x + (size_t)(n0 + 16 + lr) * IN_C + ks*32 + lg*8;
            f32x4 v00 = *reinterpret_cast<const f32x4*>(p0);
            f32x4 v01 = *reinterpret_cast<const f32x4*>(p0 + 4);
            f32x4 v10 = *reinterpret_cast<const f32x4*>(p1);
            f32x4 v11 = *reinterpret_cast<const f32x4*>(p1 + 4);
            bf16x8 a0, a1;
            #pragma unroll
            for (int j = 0; j < 4; ++j) {
                a0[j] = (bf16_t)v00[j]; a0[4+j] = (bf16_t)v01[j];
                a1[j] = (bf16_t)v10[j]; a1[4+j] = (bf16_t)v11[j];
            }
            #pragma unroll
            for (int ct = 0; ct < 4; ++ct) {
                acc[0][ct] = __builtin_amdgcn_mfma_f32_16x16x32_bf16(a0, Bf[ct][ks], acc[0][ct], 0, 0, 0);
                acc[1][ct] = __builtin_amdgcn_mfma_f32_16x16x32_bf16(a1, Bf[ct][ks], acc[1][ct], 0, 0, 0);
            }
        }

        #pragma unroll
        for (int rt = 0; rt < 2; ++rt)
            #pragma unroll
            for (int ct = 0; ct < 4; ++ct)
                #pragma unroll
                for (int r = 0; r < 4; ++r) {
                    const int row = n0 + rt*16 + lg*4 + r;
                    const int col = ct*16 + lr;
                    const float val = acc[rt][ct][r] + biasv[ct];
                    if (w < 3) kqv[(size_t)w * N_NODES * OUT_C + (size_t)row * OUT_C + col] = (bf16_t)val;
                    else       agg[(size_t)row * OUT_C + col] = val;
                }
    }
}

__global__ __launch_bounds__(256) void scanB_kernel(const unsigned* __restrict__ cnt,
                                                    unsigned* __restrict__ base_,
                                                    unsigned* __restrict__ cursor) {
    __shared__ unsigned s[256];
    const int t = threadIdx.x;
    unsigned v[7]; unsigned sum = 0;
    #pragma unroll
    for (int j = 0; j < 7; ++j) {
        const int i = t*7 + j;
        v[j] = (i < NBKT) ? cnt[i] : 0u;
        sum += v[j];
    }
    s[t] = sum; __syncthreads();
    for (int d = 1; d < 256; d <<= 1) {
        unsigned y = (t >= d) ? s[t-d] : 0u;
        __syncthreads();
        s[t] += y;
        __syncthreads();
    }
    unsigned run = s[t] - sum;   // exclusive prefix
    #pragma unroll
    for (int j = 0; j < 7; ++j) {
        const int i = t*7 + j;
        if (i < NBKT) { base_[i] = run; cursor[i] = run; run += v[j]; }
    }
    if (t == 0) base_[NBKT] = N_EDGES;
}

// payload: eid(21b) | src(17b)<<21 | dst(17b)<<38
__global__ __launch_bounds__(256) void scatterB_kernel(const int* __restrict__ ei,
                                                       unsigned* __restrict__ cursor,
                                                       u64* __restrict__ srtA) {
    __shared__ unsigned h[NBKT];
    const int t = threadIdx.x;
    for (int i = t; i < NBKT; i += 256) h[i] = 0u;
    __syncthreads();
    const int cbase = blockIdx.x * CH;
    const int* dst = ei + N_EDGES;
    for (int it = 0; it < 16; ++it) {
        const int i = cbase + (it*256 + t)*4;
        if (i < N_EDGES) {
            int4 d = *reinterpret_cast<const int4*>(dst + i);
            atomicAdd(&h[d.x >> 6], 1u);
            atomicAdd(&h[d.y >> 6], 1u);
            atomicAdd(&h[d.z >> 6], 1u);
            atomicAdd(&h[d.w >> 6], 1u);
        }
    }
    __syncthreads();
    for (int i = t; i < NBKT; i += 256) {
        unsigned c = h[i];
        if (c) h[i] = atomicAdd(&cursor[i], c);
    }
    __syncthreads();
    for (int it = 0; it < 16; ++it) {
        const int i = cbase + (it*256 + t)*4;
        if (i < N_EDGES) {
            int4 s = *reinterpret_cast<const int4*>(ei + i);
            int4 d = *reinterpret_cast<const int4*>(dst + i);
            unsigned p0 = atomicAdd(&h[d.x >> 6], 1u);
            srtA[p0] = (u64)(unsigned)(i+0) | ((u64)(unsigned)s.x << 21) | ((u64)(unsigned)d.x << 38);
            unsigned p1 = atomicAdd(&h[d.y >> 6], 1u);
            srtA[p1] = (u64)(unsigned)(i+1) | ((u64)(unsigned)s.y << 21) | ((u64)(unsigned)d.y << 38);
            unsigned p2 = atomicAdd(&h[d.z >> 6], 1u);
            srtA[p2] = (u64)(unsigned)(i+2) | ((u64)(unsigned)s.z << 21) | ((u64)(unsigned)d.z << 38);
            unsigned p3 = atomicAdd(&h[d.w >> 6], 1u);
            srtA[p3] = (u64)(unsigned)(i+3) | ((u64)(unsigned)s.w << 21) | ((u64)(unsigned)d.w << 38);
        }
    }
}

// ---------------- pass 2: within-bucket counting sort by dst&63 ----------------
__global__ __launch_bounds__(256) void sortbkt_kernel(const u64* __restrict__ srtA,
                                                      const unsigned* __restrict__ base_,
                                                      u64* __restrict__ srtB) {
    __shared__ unsigned hist[64];
    __shared__ unsigned cur[64];
    const int t = threadIdx.x;
    const unsigned s = base_[blockIdx.x];
    const unsigned e = base_[blockIdx.x + 1];
    if (t < 64) hist[t] = 0u;
    __syncthreads();
    for (unsigned i = s + t; i < e; i += 256) {
        unsigned dlo = (unsigned)(srtA[i] >> 38) & 63u;
        atomicAdd(&hist[dlo], 1u);
    }
    __syncthreads();
    if (t < 64) {  // wave 0: exclusive scan over 64 bins
        unsigned h = hist[t];
        unsigned v = h;
        #pragma unroll
        for (int off = 1; off < 64; off <<= 1) {
            unsigned y = __shfl_up(v, off);
            if (t >= off) v += y;
        }
        cur[t] = v - h;
    }
    __syncthreads();
    for (unsigned i = s + t; i < e; i += 256) {
        u64 p = srtA[i];
        unsigned dlo = (unsigned)(p >> 38) & 63u;
        unsigned pos = atomicAdd(&cur[dlo], 1u);
        srtB[s + pos] = p;
    }
}

// ---------------- Kernel B: R11 structure + non-temporal streaming ----------------
// ea/srt loads and out_ea stores marked non-temporal so the 820MB touch-once
// streams don't evict the kqv gather tables from L2.
__global__ __launch_bounds__(256) void edge_seg_kernel(
    const float* __restrict__ ea,
    const u64*   __restrict__ srt,
    const float* __restrict__ We, const float* __restrict__ be,
    const bf16_t* __restrict__ kqv,
    float* __restrict__ agg,
    float* __restrict__ out_ea)
{
    __shared__ bf16_t WeT[64][72];        // WeT[col][k] = We[k][col]
    __shared__ bf16_t ktab[4][16][72];    // per-wave staged k rows (by slot dst)
    __shared__ bf16_t qtab[4][16][72];    // per-wave staged q rows
    __shared__ bf16_t vtab[4][16][72];    // per-wave staged v rows

    const int tid = threadIdx.x;
    const int wv  = tid >> 6;
    const int l   = tid & 63;
    const int lr  = l & 15;
    const int lg  = l >> 4;
    const int row8 = l >> 3;   // 0..7
    const int part = l & 7;    // 0..7

    for (int i = tid; i < 64*64; i += 256) {
        const int k = i >> 6, c = i & 63;
        WeT[c][k] = (bf16_t)We[i];
    }
    __syncthreads();

    float bev[4];
    #pragma unroll
    for (int ct = 0; ct < 4; ++ct) bev[ct] = be[ct*16 + lr];

    const bf16_t* kT = kqv;
    const bf16_t* qT = kqv + (size_t)N_NODES * OUT_C;
    const bf16_t* vT = kqv + (size_t)2 * N_NODES * OUT_C;

    const int wid0 = blockIdx.x * 4 + wv;
    const int nw   = gridDim.x * 4;
    const int NT   = N_EDGES / 16;

    for (int t = wid0; t < NT; t += nw) {
        const int e0 = t * 16;
        const u64 p = __builtin_nontemporal_load(srt + e0 + lr);  // {eid,src,dst}
        const int eidL = (int)(p & 0x1FFFFF);
        const int srcL = (int)((p >> 21) & 0x1FFFF);
        const int dstL = (int)((p >> 38) & 0x1FFFF);

        // ---- A-fragment (slot = lr) + fused out_ea copy (all non-temporal) ----
        bf16x8 a[2];
        #pragma unroll
        for (int ks = 0; ks < 2; ++ks) {
            const size_t off = (size_t)eidL * EDGE_D + ks*32 + lg*8;
            f32x4 v0 = __builtin_nontemporal_load(reinterpret_cast<const f32x4*>(ea + off));
            f32x4 v1 = __builtin_nontemporal_load(reinterpret_cast<const f32x4*>(ea + off + 4));
            __builtin_nontemporal_store(v0, reinterpret_cast<f32x4*>(out_ea + off));
            __builtin_nontemporal_store(v1, reinterpret_cast<f32x4*>(out_ea + off + 4));
            #pragma unroll
            for (int j = 0; j < 4; ++j) { a[ks][j] = (bf16_t)v0[j]; a[ks][4+j] = (bf16_t)v1[j]; }
        }

        // ---- wide k/q/v row gathers -> per-wave LDS transpose ----
        const int src0 = __shfl(srcL, row8);
        const int src1 = __shfl(srcL, row8 + 8);
        const int dst0 = __shfl(dstL, row8);
        const int dst1 = __shfl(dstL, row8 + 8);
        uint4 gk0 = *reinterpret_cast<const uint4*>(kT + (size_t)dst0 * OUT_C + part*8);
        uint4 gk1 = *reinterpret_cast<const uint4*>(kT + (size_t)dst1 * OUT_C + part*8);
        uint4 gq0 = *reinterpret_cast<const uint4*>(qT + (size_t)src0 * OUT_C + part*8);
        uint4 gq1 = *reinterpret_cast<const uint4*>(qT + (size_t)src1 * OUT_C + part*8);
        uint4 gv0 = *reinterpret_cast<const uint4*>(vT + (size_t)src0 * OUT_C + part*8);
        uint4 gv1 = *reinterpret_cast<const uint4*>(vT + (size_t)src1 * OUT_C + part*8);
        *reinterpret_cast<uint4*>(&ktab[wv][row8    ][part*8]) = gk0;
        *reinterpret_cast<uint4*>(&ktab[wv][row8 + 8][part*8]) = gk1;
        *reinterpret_cast<uint4*>(&qtab[wv][row8    ][part*8]) = gq0;
        *reinterpret_cast<uint4*>(&qtab[wv][row8 + 8][part*8]) = gq1;
        *reinterpret_cast<uint4*>(&vtab[wv][row8    ][part*8]) = gv0;
        *reinterpret_cast<uint4*>(&vtab[wv][row8 + 8][part*8]) = gv1;

        // ---- MFMA e-projection, B-fragments from WeT ----
        f32x4 ep[4];
        #pragma unroll
        for (int ct = 0; ct < 4; ++ct) {
            bf16x8 b0 = *reinterpret_cast<const bf16x8*>(&WeT[ct*16 + lr][lg*8]);
            bf16x8 b1 = *reinterpret_cast<const bf16x8*>(&WeT[ct*16 + lr][32 + lg*8]);
            f32x4 z = (f32x4){0.f, 0.f, 0.f, 0.f};
            z = __builtin_amdgcn_mfma_f32_16x16x32_bf16(a[0], b0, z, 0, 0, 0);
            ep[ct] = __builtin_amdgcn_mfma_f32_16x16x32_bf16(a[1], b1, z, 0, 0, 0);
        }

        // dst per epilogue slot s = lg*4 + r (broadcast from slot lanes)
        int dR[4];
        #pragma unroll
        for (int r = 0; r < 4; ++r) dR[r] = __shfl(dstL, lg*4 + r);
        const int d0 = dR[0], d1 = dR[1], d2 = dR[2], d3 = dR[3];

        // ---- gate + message (k/q/v all from LDS) ----
        float val[4][4];  // [r][ct]
        #pragma unroll
        for (int r = 0; r < 4; ++r) {
            const int s = lg*4 + r;
            #pragma unroll
            for (int ct = 0; ct < 4; ++ct) {
                const int col = ct*16 + lr;
                const float kd = (float)ktab[wv][s][col];
                const float qs = (float)qtab[wv][s][col];
                const float vs = (float)vtab[wv][s][col];
                const float z  = kd + bev[ct] + qs + ep[ct][r];
                const float g  = 1.f / (1.f + __expf(-z));
                val[r][ct] = g * vs;
            }
        }

        // ---- in-lane inclusive segmented scan over r ----
        #pragma unroll
        for (int ct = 0; ct < 4; ++ct) {
            if (d1 == d0) val[1][ct] += val[0][ct];
            if (d2 == d1) val[2][ct] += val[1][ct];
            if (d3 == d2) val[3][ct] += val[2][ct];
        }

        // ---- cross-lane-group segmented scan on (S, B) monoid ----
        const int prev_d3 = __shfl(d3, l - 16);
        const int h  = (lg == 0) || (d0 != prev_d3);
        int Bs = h || (d0 != d3);
        float S[4];
        #pragma unroll
        for (int ct = 0; ct < 4; ++ct) S[ct] = val[3][ct];

        {
            float p0 = __shfl(S[0], l-16), p1 = __shfl(S[1], l-16),
                  p2 = __shfl(S[2], l-16), p3 = __shfl(S[3], l-16);
            int  pB = __shfl(Bs, l-16);
            if (lg >= 1) {
                if (!Bs) { S[0] += p0; S[1] += p1; S[2] += p2; S[3] += p3; }
                Bs |= pB;
            }
        }
        {
            float p0 = __shfl(S[0], l-32), p1 = __shfl(S[1], l-32),
                  p2 = __shfl(S[2], l-32), p3 = __shfl(S[3], l-32);
            int  pB = __shfl(Bs, l-32);
            if (lg >= 2) {
                if (!Bs) { S[0] += p0; S[1] += p1; S[2] += p2; S[3] += p3; }
                Bs |= pB;
            }
        }

        float C[4];
        #pragma unroll
        for (int ct = 0; ct < 4; ++ct) C[ct] = __shfl(S[ct], l - 16);

        if (!h) {
            #pragma unroll
            for (int r = 0; r < 4; ++r)
                if (dR[r] == d0) {
                    #pragma unroll
                    for (int ct = 0; ct < 4; ++ct) val[r][ct] += C[ct];
                }
        }

        const int next_d0 = __shfl(d0, l + 16);
        bool lastR[4];
        lastR[0] = (d1 != d0);
        lastR[1] = (d2 != d1);
        lastR[2] = (d3 != d2);
        lastR[3] = (lg == 3) ? true : (next_d0 != d3);

        #pragma unroll
        for (int r = 0; r < 4; ++r) {
            if (lastR[r]) {
                float* row = agg + (size_t)dR[r] * OUT_C + lr;
                #pragma unroll
                for (int ct = 0; ct < 4; ++ct)
                    atomicAdd(row + ct*16, val[r][ct]);
            }
        }
    }
}

// ---------------- Kernel C: finalize ----------------
__global__ __launch_bounds__(256) void finalize_kernel(
    const float* __restrict__ agg,
    const float* __restrict__ u,
    float* __restrict__ out_node,
    float* __restrict__ out_u)
{
    const int gid   = blockIdx.x * blockDim.x + threadIdx.x;
    const int total = N_NODES * OUT_C / 4;
    for (int i = gid; i < total; i += gridDim.x * blockDim.x) {
        f32x4 v = *reinterpret_cast<const f32x4*>(agg + (size_t)i * 4);
        f32x4 o;
        #pragma unroll
        for (int j = 0; j < 4; ++j) o[j] = v[j] > 0.f ? v[j] : 0.f;
        *reinterpret_cast<f32x4*>(out_node + (size_t)i * 4) = o;
    }
    if (gid < 64) out_u[gid] = u[gid];
}

extern "C" void kernel_launch(void* const* d_in, const int* in_sizes, int n_in,
                              void* d_out, int out_size, void* d_ws, size_t ws_size,
                              hipStream_t stream) {
    const float* x  = (const float*)d_in[0];
    const int*   ei = (const int*)  d_in[1];
    const float* ea = (const float*)d_in[2];
    const float* u  = (const float*)d_in[3];
    const float* Wk = (const float*)d_in[4];
    const float* bk = (const float*)d_in[5];
    const float* Wq = (const float*)d_in[6];
    const float* bq = (const float*)d_in[7];
    const float* Wv = (const float*)d_in[8];
    const float* bv = (const float*)d_in[9];
    const float* We = (const float*)d_in[10];
    const float* be = (const float*)d_in[11];
    const float* Ws = (const float*)d_in[12];
    const float* bs = (const float*)d_in[13];

    float* out      = (float*)d_out;
    float* out_node = out;
    float* out_ea   = out + (size_t)N_NODES * OUT_C;
    float* out_u    = out + (size_t)N_NODES * OUT_C + (size_t)N_EDGES * EDGE_D;

    // ws layout
    char* w = (char*)d_ws;
    bf16_t*   kqv    = (bf16_t*)w;                 // 38,400,000 B
    float*    agg    = (float*)(w + 38400000);     // 25,600,000 B -> 64,000,000
    unsigned* cnt    = (unsigned*)(w + 64000000);  //      6,252 B -> 64,008,000
    unsigned* base_  = (unsigned*)(w + 64008000);  //      6,256 B -> 64,016,000
    unsigned* cursor = (unsigned*)(w + 64016000);  //      6,252 B -> 64,024,000
    u64*      srtA   = (u64*)(w + 64024000);       // 12,800,000 B -> 76,824,000
    u64*      srtB   = (u64*)(w + 76824000);       // 12,800,000 B -> 89,624,000

    const int* dst = ei + N_EDGES;

    hipMemsetAsync(cnt, 0, NBKT * sizeof(unsigned), stream);
    node_gemm_kernel<<<1024 + NCHUNK, 256, 0, stream>>>(x, Wk, bk, Wq, bq, Wv, bv, Ws, bs,
                                                        dst, cnt, kqv, agg);
    scanB_kernel<<<1, 256, 0, stream>>>(cnt, base_, cursor);
    scatterB_kernel<<<NCHUNK, 256, 0, stream>>>(ei, cursor, srtA);
    sortbkt_kernel<<<NBKT, 256, 0, stream>>>(srtA, base_, srtB);
    edge_seg_kernel<<<2048, 256, 0, stream>>>(ea, srtB, We, be, kqv, agg, out_ea);
    finalize_kernel<<<2048, 256, 0, stream>>>(agg, u, out_node, out_u);
}